// Round 4
// baseline (189.510 us; speedup 1.0000x reference)
//
#include <hip/hip_runtime.h>

#define BATCH 64
#define SEQ   512
#define JDIM  96
#define TN    64

typedef __attribute__((ext_vector_type(8))) short bf16x8;
typedef __attribute__((ext_vector_type(4))) float f32x4;

// exact RNE float->bf16 (finite inputs)
__device__ __forceinline__ unsigned short f2bf(float f) {
  unsigned u = __float_as_uint(f);
  u += 0x7FFFu + ((u >> 16) & 1u);
  return (unsigned short)(u >> 16);
}

// ---------------- T1: xT[j][b*SEQ+m] = bf16(x[b][m][j])
__global__ __launch_bounds__(256) void transpose_in_kernel(
    const float* __restrict__ x, unsigned short* __restrict__ xT) {
  __shared__ float tile[JDIM * 65];  // [j][rr]
  const int r0 = blockIdx.x * 64;    // 512 blocks cover R = 32768 rows
  const int R = BATCH * SEQ;
  for (int idx = threadIdx.x; idx < 64 * 24; idx += 256) {
    int rr = idx / 24, jg = idx - rr * 24;
    float4 v = *(const float4*)(x + (size_t)(r0 + rr) * JDIM + 4 * jg);
    tile[(4 * jg + 0) * 65 + rr] = v.x;
    tile[(4 * jg + 1) * 65 + rr] = v.y;
    tile[(4 * jg + 2) * 65 + rr] = v.z;
    tile[(4 * jg + 3) * 65 + rr] = v.w;
  }
  __syncthreads();
  for (int idx = threadIdx.x; idx < JDIM * 8; idx += 256) {
    int jj = idx >> 3, rg = idx & 7;
    const float* t = &tile[jj * 65 + 8 * rg];
    uint4 pk;
    pk.x = (unsigned)f2bf(t[0]) | ((unsigned)f2bf(t[1]) << 16);
    pk.y = (unsigned)f2bf(t[2]) | ((unsigned)f2bf(t[3]) << 16);
    pk.z = (unsigned)f2bf(t[4]) | ((unsigned)f2bf(t[5]) << 16);
    pk.w = (unsigned)f2bf(t[6]) | ((unsigned)f2bf(t[7]) << 16);
    *(uint4*)(&xT[(size_t)jj * R + r0 + 8 * rg]) = pk;
  }
}

// ---------------- Fused, barrier-free: each wave owns C[64b x 16n] for one (j, n-strip).
// A-frags read directly from bf16 xT (global, L1/L2-served); B-frags = bf16(exp(off+pre))
// computed in registers. Row-sum L reduced across quads with shfl_xor. No LDS, no barriers:
// the unrolled K-loop lets the scheduler keep many loads in flight (fine-grained vmcnt).
__global__ __launch_bounds__(256) void fused_kernel(
    const unsigned short* __restrict__ xT,  // [J][B*SEQ] bf16
    const float* __restrict__ off,          // [J][SEQ][SEQ]
    const float* __restrict__ pre,          // [SEQ][SEQ]
    float* __restrict__ outT) {             // [J][SEQ][B]
  const int j  = blockIdx.x % JDIM;
  const int n0 = (blockIdx.x / JDIM) * TN;

  const int tid  = threadIdx.x;
  const int lane = tid & 63;
  const int wid  = tid >> 6;       // 4 waves -> 4 n-strips of 16
  const int ln   = lane & 15;
  const int quad = lane >> 4;
  const int nrow = n0 + 16 * wid + ln;   // this lane's B row (= output n col)

  const unsigned short* xTj = xT + (size_t)j * (BATCH * SEQ);
  const float* pO = off + (size_t)j * (SEQ * SEQ) + (size_t)nrow * SEQ + 8 * quad;
  const float* pP = pre + (size_t)nrow * SEQ + 8 * quad;
  const unsigned short* pA = xTj + (size_t)ln * SEQ + 8 * quad;

  f32x4 acc[4];
#pragma unroll
  for (int i = 0; i < 4; ++i) acc[i] = (f32x4){0.f, 0.f, 0.f, 0.f};
  float Lsum = 0.f;

#pragma unroll
  for (int ks = 0; ks < SEQ; ks += 32) {
    // B: this lane covers row nrow, k = ks + 8*quad .. +8  (128B contiguous per row across quads)
    const float4 o0 = *(const float4*)(pO + ks);
    const float4 o1 = *(const float4*)(pO + ks + 4);
    const float4 p0 = *(const float4*)(pP + ks);
    const float4 p1 = *(const float4*)(pP + ks + 4);
    // A: rows b = 16i+ln, same k slice (16B/lane, 64B contiguous per row across quads)
    bf16x8 af[4];
#pragma unroll
    for (int i = 0; i < 4; ++i)
      af[i] = *(const bf16x8*)(pA + (size_t)(16 * i) * SEQ + ks);

    const float e0 = __expf(o0.x + p0.x);
    const float e1 = __expf(o0.y + p0.y);
    const float e2 = __expf(o0.z + p0.z);
    const float e3 = __expf(o0.w + p0.w);
    const float e4 = __expf(o1.x + p1.x);
    const float e5 = __expf(o1.y + p1.y);
    const float e6 = __expf(o1.z + p1.z);
    const float e7 = __expf(o1.w + p1.w);
    Lsum += ((e0 + e1) + (e2 + e3)) + ((e4 + e5) + (e6 + e7));

    union { uint4 u; bf16x8 v; } bp;
    bp.u.x = (unsigned)f2bf(e0) | ((unsigned)f2bf(e1) << 16);
    bp.u.y = (unsigned)f2bf(e2) | ((unsigned)f2bf(e3) << 16);
    bp.u.z = (unsigned)f2bf(e4) | ((unsigned)f2bf(e5) << 16);
    bp.u.w = (unsigned)f2bf(e6) | ((unsigned)f2bf(e7) << 16);

#pragma unroll
    for (int i = 0; i < 4; ++i)
      acc[i] = __builtin_amdgcn_mfma_f32_16x16x32_bf16(af[i], bp.v, acc[i], 0, 0, 0);
  }

  // reduce L across the 4 quads (k-slices) -> every lane has full L(nrow)
  Lsum += __shfl_xor(Lsum, 16, 64);
  Lsum += __shfl_xor(Lsum, 32, 64);
  const float linv = 1.0f / Lsum;

  // epilogue: C/D layout col(=n)=lane&15, row(=b)=quad*4+reg; float4 along b
  float* outTj = outT + (size_t)j * (SEQ * BATCH);
#pragma unroll
  for (int i = 0; i < 4; ++i) {
    float4 v;
    v.x = acc[i][0] * linv;
    v.y = acc[i][1] * linv;
    v.z = acc[i][2] * linv;
    v.w = acc[i][3] * linv;
    *(float4*)(&outTj[(size_t)nrow * BATCH + 16 * i + 4 * quad]) = v;
  }
}

// ---------------- T2: out[b][n][j] = outT[j][n][b]
__global__ __launch_bounds__(256) void transpose_out_kernel(
    const float* __restrict__ outT, float* __restrict__ out) {
  __shared__ float tile[JDIM * 65];  // [j][b]
  const int n = blockIdx.x;          // 512 blocks
  for (int idx = threadIdx.x; idx < JDIM * 16; idx += 256) {
    int jj = idx >> 4, g = idx & 15;
    float4 v = *(const float4*)(outT + ((size_t)jj * SEQ + n) * BATCH + 4 * g);
    float* t = &tile[jj * 65 + 4 * g];
    t[0] = v.x; t[1] = v.y; t[2] = v.z; t[3] = v.w;
  }
  __syncthreads();
  for (int idx = threadIdx.x; idx < BATCH * 24; idx += 256) {
    int b = idx / 24, jg = idx - b * 24;
    float4 w;
    w.x = tile[(4 * jg + 0) * 65 + b];
    w.y = tile[(4 * jg + 1) * 65 + b];
    w.z = tile[(4 * jg + 2) * 65 + b];
    w.w = tile[(4 * jg + 3) * 65 + b];
    *(float4*)(out + ((size_t)b * SEQ + n) * JDIM + 4 * jg) = w;
  }
}

extern "C" void kernel_launch(void* const* d_in, const int* in_sizes, int n_in,
                              void* d_out, int out_size, void* d_ws, size_t ws_size,
                              hipStream_t stream) {
  const float* x   = (const float*)d_in[0];  // [64, 512, 96]
  const float* off = (const float*)d_in[1];  // [96, 512, 512]
  const float* pre = (const float*)d_in[2];  // [512, 512]
  float* out = (float*)d_out;                // [64, 512, 96]

  unsigned short* xT = (unsigned short*)d_ws;                 // bf16 [96][64*512] = 6.29 MB
  float* outT = (float*)((char*)d_ws + (size_t)JDIM * BATCH * SEQ * sizeof(unsigned short));
                                                              // f32 [96][512][64] = 12.58 MB

  transpose_in_kernel<<<BATCH * SEQ / 64, 256, 0, stream>>>(x, xT);
  fused_kernel<<<JDIM * (SEQ / TN), 256, 0, stream>>>(xT, off, pre, outT);
  transpose_out_kernel<<<SEQ, 256, 0, stream>>>(outT, out);
}